// Round 2
// baseline (287.088 us; speedup 1.0000x reference)
//
#include <hip/hip_runtime.h>

#define EPSN   1e-8f
#define MARGIN 0.2f
#define ALPHA  0.1f
#define BETA   1.05f
#define DIM    512
#define NCLS   16

typedef __attribute__((ext_vector_type(8))) short short8;
typedef __attribute__((ext_vector_type(4))) float f32x4;

__device__ __forceinline__ unsigned short f2bf(float f) {
    unsigned u = __float_as_uint(f);
    return (unsigned short)((u + 0x7FFFu + ((u >> 16) & 1u)) >> 16);  // RNE
}
__device__ __forceinline__ short8 pack8(float4 x0, float4 x1) {
    short8 r;
    r[0] = (short)f2bf(x0.x); r[1] = (short)f2bf(x0.y);
    r[2] = (short)f2bf(x0.z); r[3] = (short)f2bf(x0.w);
    r[4] = (short)f2bf(x1.x); r[5] = (short)f2bf(x1.y);
    r[6] = (short)f2bf(x1.z); r[7] = (short)f2bf(x1.w);
    return r;
}

// ---------------- Kernel 1: triplet loss partial sum -> scal[0] ----------------
// 4 rows in flight per wave: lane = (row g = lane>>4, segment = lane&15).
// Each lane covers 32 contiguous floats of its row -> 24 independent dwordx4
// loads per iteration; reduction is 4 shfl_xor steps within 16-lane groups.
__global__ __launch_bounds__(256) void k_triplet(const float* __restrict__ A,
                                                 const float* __restrict__ P,
                                                 const float* __restrict__ Q,
                                                 float* __restrict__ scal, int N) {
    __shared__ float red[4];
    int t = threadIdx.x, lane = t & 63, wid = t >> 6;
    int g = lane >> 4, seg = lane & 15;
    int gw = blockIdx.x * 4 + wid, nw = gridDim.x * 4;
    int nquad = N >> 2;
    float tri = 0.f;
    for (int quad = gw; quad < nquad; quad += nw) {
        size_t base = (size_t)(quad * 4 + g) * DIM + seg * 32;
        float4 a[8], p[8], q[8];
#pragma unroll
        for (int i = 0; i < 8; ++i) a[i] = *(const float4*)(A + base + i * 4);
#pragma unroll
        for (int i = 0; i < 8; ++i) p[i] = *(const float4*)(P + base + i * 4);
#pragma unroll
        for (int i = 0; i < 8; ++i) q[i] = *(const float4*)(Q + base + i * 4);
        float sa = 0, sp = 0, sn = 0, dap = 0, dan = 0;
#pragma unroll
        for (int i = 0; i < 8; ++i) {
            sa  = fmaf(a[i].x,a[i].x, fmaf(a[i].y,a[i].y, fmaf(a[i].z,a[i].z, fmaf(a[i].w,a[i].w, sa))));
            sp  = fmaf(p[i].x,p[i].x, fmaf(p[i].y,p[i].y, fmaf(p[i].z,p[i].z, fmaf(p[i].w,p[i].w, sp))));
            sn  = fmaf(q[i].x,q[i].x, fmaf(q[i].y,q[i].y, fmaf(q[i].z,q[i].z, fmaf(q[i].w,q[i].w, sn))));
            dap = fmaf(a[i].x,p[i].x, fmaf(a[i].y,p[i].y, fmaf(a[i].z,p[i].z, fmaf(a[i].w,p[i].w, dap))));
            dan = fmaf(a[i].x,q[i].x, fmaf(a[i].y,q[i].y, fmaf(a[i].z,q[i].z, fmaf(a[i].w,q[i].w, dan))));
        }
#pragma unroll
        for (int o = 1; o < 16; o <<= 1) {
            sa  += __shfl_xor(sa,  o);
            sp  += __shfl_xor(sp,  o);
            sn  += __shfl_xor(sn,  o);
            dap += __shfl_xor(dap, o);
            dan += __shfl_xor(dan, o);
        }
        if (seg == 0) {
            float na = fmaxf(sqrtf(sa), EPSN);
            float np = fmaxf(sqrtf(sp), EPSN);
            float nn = fmaxf(sqrtf(sn), EPSN);
            float posd = 1.f - dap / (na * np);
            float negd = 1.f - dan / (na * nn);
            tri += fmaxf(posd - negd + MARGIN, 0.f);
        }
    }
    tri += __shfl_xor(tri, 16);   // combine lanes 0,16,32,48 (seg==0 holders)
    tri += __shfl_xor(tri, 32);
    if (lane == 0) red[wid] = tri;
    __syncthreads();
    if (t == 0) atomicAdd(&scal[0], red[0] + red[1] + red[2] + red[3]);
}

// ---------------- Kernel 2: per-class sums + counts ----------------
// 8 rows per iteration for MLP; each thread owns float2 column slot exclusively.
__global__ __launch_bounds__(256) void k_segsum(const float* __restrict__ E,
                                                const int* __restrict__ L,
                                                float* __restrict__ sums,
                                                int* __restrict__ counts, int N) {
    __shared__ float acc[NCLS * DIM];
    __shared__ int cl[NCLS];
    int t = threadIdx.x;
    for (int i = t; i < NCLS * DIM; i += 256) acc[i] = 0.f;
    if (t < NCLS) cl[t] = 0;
    __syncthreads();
    for (int r = blockIdx.x * 8; r < N; r += gridDim.x * 8) {
        int l[8];
        float2 v[8];
#pragma unroll
        for (int i = 0; i < 8; ++i) l[i] = L[r + i];
#pragma unroll
        for (int i = 0; i < 8; ++i)
            v[i] = *((const float2*)(E + (size_t)(r + i) * DIM) + t);
#pragma unroll
        for (int i = 0; i < 8; ++i) {
            float2* p = (float2*)&acc[l[i] * DIM] + t;
            p->x += v[i].x; p->y += v[i].y;
        }
        if (t == 0) {
#pragma unroll
            for (int i = 0; i < 8; ++i) cl[l[i]]++;
        }
    }
    __syncthreads();
    for (int i = t; i < NCLS * DIM; i += 256) atomicAdd(&sums[i], acc[i]);
    if (t < NCLS) atomicAdd(&counts[t], cl[t]);
}

// ---------------- Kernel 3 (tiny): centroids, normalize, pair matrix, cnt, n_terms ----------------
__global__ __launch_bounds__(256) void k_centroid(const float* __restrict__ sums,
                                                  const int* __restrict__ counts,
                                                  float* __restrict__ ncn_g,
                                                  float* __restrict__ pairf_g,
                                                  float* __restrict__ cntf_g,
                                                  float* __restrict__ scal) {
    __shared__ float ncn[NCLS * DIM];
    __shared__ float red[256];
    int t = threadIdx.x;
    for (int c = 0; c < NCLS; ++c) {
        float inv = 1.f / fmaxf((float)counts[c], 1.f);
        float s0 = sums[c * DIM + t] * inv;
        float s1 = sums[c * DIM + 256 + t] * inv;
        ncn[c * DIM + t] = s0;
        ncn[c * DIM + 256 + t] = s1;
        red[t] = s0 * s0 + s1 * s1;
        __syncthreads();
        for (int o = 128; o > 0; o >>= 1) { if (t < o) red[t] += red[t + o]; __syncthreads(); }
        float rs = 1.f / fmaxf(sqrtf(red[0]), EPSN);
        ncn[c * DIM + t] *= rs;
        ncn[c * DIM + 256 + t] *= rs;
        __syncthreads();
    }
    for (int i = t; i < NCLS * DIM; i += 256) ncn_g[i] = ncn[i];
    __syncthreads();
    // pair matrix in full fp32 (binary decisions are sensitive -> no bf16 here)
    int i = t >> 4, j = t & 15;
    float dot = 0.f;
    for (int d = 0; d < DIM; ++d) dot += ncn[i * DIM + d] * ncn[j * DIM + d];
    float cd = 1.f - dot;
    float pf = (cd <= BETA && i != j && counts[i] > 0 && counts[j] > 0) ? 1.f : 0.f;
    pairf_g[t] = pf;
    red[t] = pf;
    __syncthreads();
    if (t < NCLS) {
        float s = 0.f;
        for (int k = 0; k < NCLS; ++k) s += red[t * 16 + k];
        cntf_g[t] = s;
    }
    __syncthreads();
    if (t == 0) {
        float nt = 0.f;
        for (int k = 0; k < NCLS; ++k) nt += cntf_g[k] * (float)counts[k];
        scal[3] = nt;
        scal[4] = 1.f / fmaxf(nt, 1.f);
    }
}

// ---------------- Kernel 4: D = ê·ncn^T via bf16 MFMA; intra/inter partials ----------------
__global__ __launch_bounds__(256) void k_atn(const float* __restrict__ E,
                                             const int* __restrict__ L,
                                             const float* __restrict__ ncn,
                                             const float* __restrict__ pairf,
                                             const float* __restrict__ cntf,
                                             float* __restrict__ scal, int N) {
    __shared__ float pr[NCLS * NCLS];
    __shared__ float cf[NCLS];
    __shared__ float red[8];
    int t = threadIdx.x, lane = t & 63, wid = t >> 6;
    pr[t] = pairf[t];
    if (t < NCLS) cf[t] = cntf[t];
    __syncthreads();

    int col = lane & 15;      // A-row within tile == B-col (class)
    int kg = lane >> 4;       // k-group 0..3
    short8 bfr[16];           // B fragments for all 16 K-steps, held in VGPRs
#pragma unroll
    for (int s = 0; s < 16; ++s) {
        const float4* q = (const float4*)(ncn + col * DIM + s * 32 + kg * 8);
        bfr[s] = pack8(q[0], q[1]);
    }

    float inter = 0.f, intra = 0.f;
    int gw = blockIdx.x * 4 + wid, nw = gridDim.x * 4;
    int ntile = N >> 4;
    for (int tile = gw; tile < ntile; tile += nw) {
        int rowb = tile << 4;
        const float* ar = E + (size_t)(rowb + col) * DIM + kg * 8;
        f32x4 acc0 = {0.f, 0.f, 0.f, 0.f}, acc1 = {0.f, 0.f, 0.f, 0.f};
        float ss0 = 0.f, ss1 = 0.f;
#pragma unroll
        for (int s = 0; s < 16; s += 2) {
            float4 x0 = *(const float4*)(ar + s * 32);
            float4 x1 = *(const float4*)(ar + s * 32 + 4);
            float4 y0 = *(const float4*)(ar + (s + 1) * 32);
            float4 y1 = *(const float4*)(ar + (s + 1) * 32 + 4);
            ss0 = fmaf(x0.x, x0.x, ss0); ss0 = fmaf(x0.y, x0.y, ss0);
            ss0 = fmaf(x0.z, x0.z, ss0); ss0 = fmaf(x0.w, x0.w, ss0);
            ss0 = fmaf(x1.x, x1.x, ss0); ss0 = fmaf(x1.y, x1.y, ss0);
            ss0 = fmaf(x1.z, x1.z, ss0); ss0 = fmaf(x1.w, x1.w, ss0);
            ss1 = fmaf(y0.x, y0.x, ss1); ss1 = fmaf(y0.y, y0.y, ss1);
            ss1 = fmaf(y0.z, y0.z, ss1); ss1 = fmaf(y0.w, y0.w, ss1);
            ss1 = fmaf(y1.x, y1.x, ss1); ss1 = fmaf(y1.y, y1.y, ss1);
            ss1 = fmaf(y1.w, y1.w, ss1); ss1 = fmaf(y1.z, y1.z, ss1);
            acc0 = __builtin_amdgcn_mfma_f32_16x16x32_bf16(pack8(x0, x1), bfr[s],     acc0, 0, 0, 0);
            acc1 = __builtin_amdgcn_mfma_f32_16x16x32_bf16(pack8(y0, y1), bfr[s + 1], acc1, 0, 0, 0);
        }
        f32x4 acc = acc0 + acc1;
        float ss = ss0 + ss1;
        // lane holds sumsq partial of row (lane&15) over its k-quarter; combine quarters
        ss += __shfl_xor(ss, 16);
        ss += __shfl_xor(ss, 32);
#pragma unroll
        for (int reg = 0; reg < 4; ++reg) {
            int row = kg * 4 + reg;            // C/D: col=lane&15, row=(lane>>4)*4+reg
            float s2 = __shfl(ss, row);        // lane 'row' holds sumsq of row 'row'
            float rinv = 1.f / fmaxf(sqrtf(s2), EPSN);
            float d = 1.f - acc[reg] * rinv;
            int lab = L[rowb + row];
            inter += pr[lab * 16 + col] * fmaxf(BETA - d, 0.f);
            if (col == lab) intra += cf[lab] * fmaxf(d - ALPHA, 0.f);
        }
    }
#pragma unroll
    for (int o = 32; o > 0; o >>= 1) {
        inter += __shfl_xor(inter, o);
        intra += __shfl_xor(intra, o);
    }
    if (lane == 0) { red[wid] = intra; red[4 + wid] = inter; }
    __syncthreads();
    if (t == 0) {
        atomicAdd(&scal[1], red[0] + red[1] + red[2] + red[3]);
        atomicAdd(&scal[2], red[4] + red[5] + red[6] + red[7]);
    }
}

// ---------------- Kernel 5: combine ----------------
__global__ void k_final(const float* __restrict__ scal, float* __restrict__ out, float invN) {
    float tri = scal[0] * invN;
    float atn = (scal[3] > 0.f) ? (scal[1] + scal[2]) * scal[4] : 0.f;
    out[0] = tri + atn;
}

extern "C" void kernel_launch(void* const* d_in, const int* in_sizes, int n_in,
                              void* d_out, int out_size, void* d_ws, size_t ws_size,
                              hipStream_t stream) {
    const float* A = (const float*)d_in[0];
    const float* P = (const float*)d_in[1];
    const float* Q = (const float*)d_in[2];
    const float* E = (const float*)d_in[3];
    const int*   L = (const int*)d_in[4];
    int N = in_sizes[0] / DIM;

    char* ws = (char*)d_ws;
    float* sums   = (float*)ws;             // 8192 f32 = 32768 B
    int*   counts = (int*)(ws + 32768);     // 16 i32
    float* scal   = (float*)(ws + 32832);   // [0]=tri [1]=intra [2]=inter [3]=n_terms [4]=1/max(n,1)
    float* ncn    = (float*)(ws + 36864);   // 8192 f32 normalized centroids
    float* pairf  = (float*)(ws + 69632);   // 256 f32
    float* cntf   = (float*)(ws + 70656);   // 16 f32

    hipMemsetAsync(d_ws, 0, 36864, stream); // zero accumulators every call

    // Order matters for L3: stream A/P/Q first, then both E readers back-to-back
    // so E (128 MB) stays resident in the 256 MB L3 between segsum and atn.
    k_triplet <<<2048, 256, 0, stream>>>(A, P, Q, scal, N);
    k_segsum  <<<256,  256, 0, stream>>>(E, L, sums, counts, N);
    k_centroid<<<1,    256, 0, stream>>>(sums, counts, ncn, pairf, cntf, scal);
    k_atn     <<<512,  256, 0, stream>>>(E, L, ncn, pairf, cntf, scal, N);
    k_final   <<<1, 1, 0, stream>>>(scal, (float*)d_out, 1.f / (float)N);
}

// Round 3
// 195.417 us; speedup vs baseline: 1.4691x; 1.4691x over previous
//
#include <hip/hip_runtime.h>

#define EPSN   1e-8f
#define MARGIN 0.2f
#define ALPHA  0.1f
#define BETA   1.05f
#define DIM    512
#define NCLS   16

typedef __attribute__((ext_vector_type(8))) short short8;
typedef __attribute__((ext_vector_type(4))) float f32x4;

__device__ __forceinline__ unsigned short f2bf(float f) {
    unsigned u = __float_as_uint(f);
    return (unsigned short)((u + 0x7FFFu + ((u >> 16) & 1u)) >> 16);  // RNE
}
__device__ __forceinline__ short8 pack8(float4 x0, float4 x1) {
    short8 r;
    r[0] = (short)f2bf(x0.x); r[1] = (short)f2bf(x0.y);
    r[2] = (short)f2bf(x0.z); r[3] = (short)f2bf(x0.w);
    r[4] = (short)f2bf(x1.x); r[5] = (short)f2bf(x1.y);
    r[6] = (short)f2bf(x1.z); r[7] = (short)f2bf(x1.w);
    return r;
}

// ---------------- Kernel 1: triplet loss partial sum -> scal[0] ----------------
// 4 rows per wave iteration: group g = lane>>4 owns row (quad*4+g); within the
// group, lane seg reads float4 at seg*4 + i*64 floats -> each load instruction
// covers 4 x 256B fully-used contiguous chunks (coalesced), 24 loads in flight.
// Reduction: 4 shfl_xor steps within 16-lane groups (groups reduce in parallel).
__global__ __launch_bounds__(256) void k_triplet(const float* __restrict__ A,
                                                 const float* __restrict__ P,
                                                 const float* __restrict__ Q,
                                                 float* __restrict__ scal, int N) {
    __shared__ float red[4];
    int t = threadIdx.x, lane = t & 63, wid = t >> 6;
    int g = lane >> 4, seg = lane & 15;
    int gw = blockIdx.x * 4 + wid, nw = gridDim.x * 4;
    int nquad = N >> 2;
    float tri = 0.f;
    for (int quad = gw; quad < nquad; quad += nw) {
        size_t base = (size_t)(quad * 4 + g) * DIM + seg * 4;
        float4 a[8], p[8], q[8];
#pragma unroll
        for (int i = 0; i < 8; ++i) a[i] = *(const float4*)(A + base + i * 64);
#pragma unroll
        for (int i = 0; i < 8; ++i) p[i] = *(const float4*)(P + base + i * 64);
#pragma unroll
        for (int i = 0; i < 8; ++i) q[i] = *(const float4*)(Q + base + i * 64);
        float sa = 0, sp = 0, sn = 0, dap = 0, dan = 0;
#pragma unroll
        for (int i = 0; i < 8; ++i) {
            sa  = fmaf(a[i].x,a[i].x, fmaf(a[i].y,a[i].y, fmaf(a[i].z,a[i].z, fmaf(a[i].w,a[i].w, sa))));
            sp  = fmaf(p[i].x,p[i].x, fmaf(p[i].y,p[i].y, fmaf(p[i].z,p[i].z, fmaf(p[i].w,p[i].w, sp))));
            sn  = fmaf(q[i].x,q[i].x, fmaf(q[i].y,q[i].y, fmaf(q[i].z,q[i].z, fmaf(q[i].w,q[i].w, sn))));
            dap = fmaf(a[i].x,p[i].x, fmaf(a[i].y,p[i].y, fmaf(a[i].z,p[i].z, fmaf(a[i].w,p[i].w, dap))));
            dan = fmaf(a[i].x,q[i].x, fmaf(a[i].y,q[i].y, fmaf(a[i].z,q[i].z, fmaf(a[i].w,q[i].w, dan))));
        }
#pragma unroll
        for (int o = 1; o < 16; o <<= 1) {
            sa  += __shfl_xor(sa,  o);
            sp  += __shfl_xor(sp,  o);
            sn  += __shfl_xor(sn,  o);
            dap += __shfl_xor(dap, o);
            dan += __shfl_xor(dan, o);
        }
        if (seg == 0) {
            float na = fmaxf(sqrtf(sa), EPSN);
            float np = fmaxf(sqrtf(sp), EPSN);
            float nn = fmaxf(sqrtf(sn), EPSN);
            float posd = 1.f - dap / (na * np);
            float negd = 1.f - dan / (na * nn);
            tri += fmaxf(posd - negd + MARGIN, 0.f);
        }
    }
    tri += __shfl_xor(tri, 16);   // combine lanes 0,16,32,48 (seg==0 holders)
    tri += __shfl_xor(tri, 32);
    if (lane == 0) red[wid] = tri;
    __syncthreads();
    if (t == 0) atomicAdd(&scal[0], red[0] + red[1] + red[2] + red[3]);
}

// ---------------- Kernel 2: per-class sums + counts ----------------
// 8 rows per iteration for MLP; each thread owns float2 column slot exclusively.
__global__ __launch_bounds__(256) void k_segsum(const float* __restrict__ E,
                                                const int* __restrict__ L,
                                                float* __restrict__ sums,
                                                int* __restrict__ counts, int N) {
    __shared__ float acc[NCLS * DIM];
    __shared__ int cl[NCLS];
    int t = threadIdx.x;
    for (int i = t; i < NCLS * DIM; i += 256) acc[i] = 0.f;
    if (t < NCLS) cl[t] = 0;
    __syncthreads();
    for (int r = blockIdx.x * 8; r < N; r += gridDim.x * 8) {
        int l[8];
        float2 v[8];
#pragma unroll
        for (int i = 0; i < 8; ++i) l[i] = L[r + i];
#pragma unroll
        for (int i = 0; i < 8; ++i)
            v[i] = *((const float2*)(E + (size_t)(r + i) * DIM) + t);
#pragma unroll
        for (int i = 0; i < 8; ++i) {
            float2* p = (float2*)&acc[l[i] * DIM] + t;
            p->x += v[i].x; p->y += v[i].y;
        }
        if (t == 0) {
#pragma unroll
            for (int i = 0; i < 8; ++i) cl[l[i]]++;
        }
    }
    __syncthreads();
    for (int i = t; i < NCLS * DIM; i += 256) atomicAdd(&sums[i], acc[i]);
    if (t < NCLS) atomicAdd(&counts[t], cl[t]);
}

// ---------------- Kernel 3 (tiny): centroids, normalize, pair matrix, cnt, n_terms ----------------
__global__ __launch_bounds__(256) void k_centroid(const float* __restrict__ sums,
                                                  const int* __restrict__ counts,
                                                  float* __restrict__ ncn_g,
                                                  float* __restrict__ pairf_g,
                                                  float* __restrict__ cntf_g,
                                                  float* __restrict__ scal) {
    __shared__ float ncn[NCLS * DIM];
    __shared__ float red[256];
    int t = threadIdx.x;
    for (int c = 0; c < NCLS; ++c) {
        float inv = 1.f / fmaxf((float)counts[c], 1.f);
        float s0 = sums[c * DIM + t] * inv;
        float s1 = sums[c * DIM + 256 + t] * inv;
        ncn[c * DIM + t] = s0;
        ncn[c * DIM + 256 + t] = s1;
        red[t] = s0 * s0 + s1 * s1;
        __syncthreads();
        for (int o = 128; o > 0; o >>= 1) { if (t < o) red[t] += red[t + o]; __syncthreads(); }
        float rs = 1.f / fmaxf(sqrtf(red[0]), EPSN);
        ncn[c * DIM + t] *= rs;
        ncn[c * DIM + 256 + t] *= rs;
        __syncthreads();
    }
    for (int i = t; i < NCLS * DIM; i += 256) ncn_g[i] = ncn[i];
    __syncthreads();
    // pair matrix in full fp32 (binary decisions are sensitive -> no bf16 here)
    int i = t >> 4, j = t & 15;
    float dot = 0.f;
    for (int d = 0; d < DIM; ++d) dot += ncn[i * DIM + d] * ncn[j * DIM + d];
    float cd = 1.f - dot;
    float pf = (cd <= BETA && i != j && counts[i] > 0 && counts[j] > 0) ? 1.f : 0.f;
    pairf_g[t] = pf;
    red[t] = pf;
    __syncthreads();
    if (t < NCLS) {
        float s = 0.f;
        for (int k = 0; k < NCLS; ++k) s += red[t * 16 + k];
        cntf_g[t] = s;
    }
    __syncthreads();
    if (t == 0) {
        float nt = 0.f;
        for (int k = 0; k < NCLS; ++k) nt += cntf_g[k] * (float)counts[k];
        scal[3] = nt;
        scal[4] = 1.f / fmaxf(nt, 1.f);
    }
}

// ---------------- Kernel 4: D = ê·ncn^T via bf16 MFMA; intra/inter partials ----------------
__global__ __launch_bounds__(256) void k_atn(const float* __restrict__ E,
                                             const int* __restrict__ L,
                                             const float* __restrict__ ncn,
                                             const float* __restrict__ pairf,
                                             const float* __restrict__ cntf,
                                             float* __restrict__ scal, int N) {
    __shared__ float pr[NCLS * NCLS];
    __shared__ float cf[NCLS];
    __shared__ float red[8];
    int t = threadIdx.x, lane = t & 63, wid = t >> 6;
    pr[t] = pairf[t];
    if (t < NCLS) cf[t] = cntf[t];
    __syncthreads();

    int col = lane & 15;      // A-row within tile == B-col (class)
    int kg = lane >> 4;       // k-group 0..3
    short8 bfr[16];           // B fragments for all 16 K-steps, held in VGPRs
#pragma unroll
    for (int s = 0; s < 16; ++s) {
        const float4* q = (const float4*)(ncn + col * DIM + s * 32 + kg * 8);
        bfr[s] = pack8(q[0], q[1]);
    }

    float inter = 0.f, intra = 0.f;
    int gw = blockIdx.x * 4 + wid, nw = gridDim.x * 4;
    int ntile = N >> 4;
    for (int tile = gw; tile < ntile; tile += nw) {
        int rowb = tile << 4;
        const float* ar = E + (size_t)(rowb + col) * DIM + kg * 8;
        f32x4 acc0 = {0.f, 0.f, 0.f, 0.f}, acc1 = {0.f, 0.f, 0.f, 0.f};
        float ss0 = 0.f, ss1 = 0.f;
#pragma unroll
        for (int s = 0; s < 16; s += 2) {
            float4 x0 = *(const float4*)(ar + s * 32);
            float4 x1 = *(const float4*)(ar + s * 32 + 4);
            float4 y0 = *(const float4*)(ar + (s + 1) * 32);
            float4 y1 = *(const float4*)(ar + (s + 1) * 32 + 4);
            ss0 = fmaf(x0.x, x0.x, ss0); ss0 = fmaf(x0.y, x0.y, ss0);
            ss0 = fmaf(x0.z, x0.z, ss0); ss0 = fmaf(x0.w, x0.w, ss0);
            ss0 = fmaf(x1.x, x1.x, ss0); ss0 = fmaf(x1.y, x1.y, ss0);
            ss0 = fmaf(x1.z, x1.z, ss0); ss0 = fmaf(x1.w, x1.w, ss0);
            ss1 = fmaf(y0.x, y0.x, ss1); ss1 = fmaf(y0.y, y0.y, ss1);
            ss1 = fmaf(y0.z, y0.z, ss1); ss1 = fmaf(y0.w, y0.w, ss1);
            ss1 = fmaf(y1.x, y1.x, ss1); ss1 = fmaf(y1.y, y1.y, ss1);
            ss1 = fmaf(y1.z, y1.z, ss1); ss1 = fmaf(y1.w, y1.w, ss1);
            acc0 = __builtin_amdgcn_mfma_f32_16x16x32_bf16(pack8(x0, x1), bfr[s],     acc0, 0, 0, 0);
            acc1 = __builtin_amdgcn_mfma_f32_16x16x32_bf16(pack8(y0, y1), bfr[s + 1], acc1, 0, 0, 0);
        }
        f32x4 acc = acc0 + acc1;
        float ss = ss0 + ss1;
        // lane holds sumsq partial of row (lane&15) over its k-quarter; combine quarters
        ss += __shfl_xor(ss, 16);
        ss += __shfl_xor(ss, 32);
#pragma unroll
        for (int reg = 0; reg < 4; ++reg) {
            int row = kg * 4 + reg;            // C/D: col=lane&15, row=(lane>>4)*4+reg
            float s2 = __shfl(ss, row);        // lane 'row' holds sumsq of row 'row'
            float rinv = 1.f / fmaxf(sqrtf(s2), EPSN);
            float d = 1.f - acc[reg] * rinv;
            int lab = L[rowb + row];
            inter += pr[lab * 16 + col] * fmaxf(BETA - d, 0.f);
            if (col == lab) intra += cf[lab] * fmaxf(d - ALPHA, 0.f);
        }
    }
#pragma unroll
    for (int o = 32; o > 0; o >>= 1) {
        inter += __shfl_xor(inter, o);
        intra += __shfl_xor(intra, o);
    }
    if (lane == 0) { red[wid] = intra; red[4 + wid] = inter; }
    __syncthreads();
    if (t == 0) {
        atomicAdd(&scal[1], red[0] + red[1] + red[2] + red[3]);
        atomicAdd(&scal[2], red[4] + red[5] + red[6] + red[7]);
    }
}

// ---------------- Kernel 5: combine ----------------
__global__ void k_final(const float* __restrict__ scal, float* __restrict__ out, float invN) {
    float tri = scal[0] * invN;
    float atn = (scal[3] > 0.f) ? (scal[1] + scal[2]) * scal[4] : 0.f;
    out[0] = tri + atn;
}

extern "C" void kernel_launch(void* const* d_in, const int* in_sizes, int n_in,
                              void* d_out, int out_size, void* d_ws, size_t ws_size,
                              hipStream_t stream) {
    const float* A = (const float*)d_in[0];
    const float* P = (const float*)d_in[1];
    const float* Q = (const float*)d_in[2];
    const float* E = (const float*)d_in[3];
    const int*   L = (const int*)d_in[4];
    int N = in_sizes[0] / DIM;

    char* ws = (char*)d_ws;
    float* sums   = (float*)ws;             // 8192 f32 = 32768 B
    int*   counts = (int*)(ws + 32768);     // 16 i32
    float* scal   = (float*)(ws + 32832);   // [0]=tri [1]=intra [2]=inter [3]=n_terms [4]=1/max(n,1)
    float* ncn    = (float*)(ws + 36864);   // 8192 f32 normalized centroids
    float* pairf  = (float*)(ws + 69632);   // 256 f32
    float* cntf   = (float*)(ws + 70656);   // 16 f32

    hipMemsetAsync(d_ws, 0, 36864, stream); // zero accumulators every call

    // Order matters for L3: stream A/P/Q first, then both E readers back-to-back
    // so E (128 MB) stays resident in the 256 MB L3 between segsum and atn.
    k_triplet <<<2048, 256, 0, stream>>>(A, P, Q, scal, N);
    k_segsum  <<<512,  256, 0, stream>>>(E, L, sums, counts, N);
    k_centroid<<<1,    256, 0, stream>>>(sums, counts, ncn, pairf, cntf, scal);
    k_atn     <<<512,  256, 0, stream>>>(E, L, ncn, pairf, cntf, scal, N);
    k_final   <<<1, 1, 0, stream>>>(scal, (float*)d_out, 1.f / (float)N);
}

// Round 5
// 186.675 us; speedup vs baseline: 1.5379x; 1.0468x over previous
//
#include <hip/hip_runtime.h>

#define EPSN   1e-8f
#define MARGIN 0.2f
#define ALPHA  0.1f
#define BETA   1.05f
#define DIM    512
#define NCLS   16

typedef __attribute__((ext_vector_type(8))) short short8;
typedef __attribute__((ext_vector_type(4))) float f32x4;
typedef __attribute__((ext_vector_type(4))) float nf4;   // native vec for nontemporal builtins

__device__ __forceinline__ unsigned short f2bf(float f) {
    unsigned u = __float_as_uint(f);
    return (unsigned short)((u + 0x7FFFu + ((u >> 16) & 1u)) >> 16);  // RNE
}
__device__ __forceinline__ short8 pack8(float4 x0, float4 x1) {
    short8 r;
    r[0] = (short)f2bf(x0.x); r[1] = (short)f2bf(x0.y);
    r[2] = (short)f2bf(x0.z); r[3] = (short)f2bf(x0.w);
    r[4] = (short)f2bf(x1.x); r[5] = (short)f2bf(x1.y);
    r[6] = (short)f2bf(x1.z); r[7] = (short)f2bf(x1.w);
    return r;
}

// ---------------- Kernel 1: triplet loss partial sum -> scal[0] ----------------
// Experiment R4 (rebuilt): (a) nontemporal loads (single-touch data, skip L3
// alloc); (b) 2-deep pipeline: each wave owns exactly 2 quads (grid 2048), all
// 48 loads issued before the first reduction so reduce(quad0) hides under
// quad1's in-flight loads. Mapping unchanged from R3 (coalesced 256B chunks).
__global__ __launch_bounds__(256) void k_triplet(const float* __restrict__ A,
                                                 const float* __restrict__ P,
                                                 const float* __restrict__ Q,
                                                 float* __restrict__ scal, int N) {
    __shared__ float red[4];
    int t = threadIdx.x, lane = t & 63, wid = t >> 6;
    int g = lane >> 4, seg = lane & 15;
    int gw = blockIdx.x * 4 + wid, nw = gridDim.x * 4;
    int nquad = N >> 2;
    float tri = 0.f;
    for (int quad = gw; quad < nquad; quad += 2 * nw) {
        int quadB = quad + nw;
        bool hasB = quadB < nquad;
        size_t base0 = (size_t)(quad * 4 + g) * DIM + seg * 4;
        // second batch: clamp address when absent (loads still issued, values unused)
        size_t base1 = hasB ? ((size_t)(quadB * 4 + g) * DIM + seg * 4) : base0;
        nf4 a0[8], p0[8], q0[8], a1[8], p1[8], q1[8];
#pragma unroll
        for (int i = 0; i < 8; ++i) a0[i] = __builtin_nontemporal_load((const nf4*)(A + base0 + i * 64));
#pragma unroll
        for (int i = 0; i < 8; ++i) p0[i] = __builtin_nontemporal_load((const nf4*)(P + base0 + i * 64));
#pragma unroll
        for (int i = 0; i < 8; ++i) q0[i] = __builtin_nontemporal_load((const nf4*)(Q + base0 + i * 64));
#pragma unroll
        for (int i = 0; i < 8; ++i) a1[i] = __builtin_nontemporal_load((const nf4*)(A + base1 + i * 64));
#pragma unroll
        for (int i = 0; i < 8; ++i) p1[i] = __builtin_nontemporal_load((const nf4*)(P + base1 + i * 64));
#pragma unroll
        for (int i = 0; i < 8; ++i) q1[i] = __builtin_nontemporal_load((const nf4*)(Q + base1 + i * 64));

        // ---- reduce quad 0 (quad 1's loads still in flight) ----
        {
            float sa = 0, sp = 0, sn = 0, dap = 0, dan = 0;
#pragma unroll
            for (int i = 0; i < 8; ++i) {
                sa  = fmaf(a0[i].x,a0[i].x, fmaf(a0[i].y,a0[i].y, fmaf(a0[i].z,a0[i].z, fmaf(a0[i].w,a0[i].w, sa))));
                sp  = fmaf(p0[i].x,p0[i].x, fmaf(p0[i].y,p0[i].y, fmaf(p0[i].z,p0[i].z, fmaf(p0[i].w,p0[i].w, sp))));
                sn  = fmaf(q0[i].x,q0[i].x, fmaf(q0[i].y,q0[i].y, fmaf(q0[i].z,q0[i].z, fmaf(q0[i].w,q0[i].w, sn))));
                dap = fmaf(a0[i].x,p0[i].x, fmaf(a0[i].y,p0[i].y, fmaf(a0[i].z,p0[i].z, fmaf(a0[i].w,p0[i].w, dap))));
                dan = fmaf(a0[i].x,q0[i].x, fmaf(a0[i].y,q0[i].y, fmaf(a0[i].z,q0[i].z, fmaf(a0[i].w,q0[i].w, dan))));
            }
#pragma unroll
            for (int o = 1; o < 16; o <<= 1) {
                sa  += __shfl_xor(sa,  o);
                sp  += __shfl_xor(sp,  o);
                sn  += __shfl_xor(sn,  o);
                dap += __shfl_xor(dap, o);
                dan += __shfl_xor(dan, o);
            }
            if (seg == 0) {
                float na = fmaxf(sqrtf(sa), EPSN);
                float np = fmaxf(sqrtf(sp), EPSN);
                float nn = fmaxf(sqrtf(sn), EPSN);
                float posd = 1.f - dap / (na * np);
                float negd = 1.f - dan / (na * nn);
                tri += fmaxf(posd - negd + MARGIN, 0.f);
            }
        }
        // ---- reduce quad 1 ----
        if (hasB) {
            float sa = 0, sp = 0, sn = 0, dap = 0, dan = 0;
#pragma unroll
            for (int i = 0; i < 8; ++i) {
                sa  = fmaf(a1[i].x,a1[i].x, fmaf(a1[i].y,a1[i].y, fmaf(a1[i].z,a1[i].z, fmaf(a1[i].w,a1[i].w, sa))));
                sp  = fmaf(p1[i].x,p1[i].x, fmaf(p1[i].y,p1[i].y, fmaf(p1[i].z,p1[i].z, fmaf(p1[i].w,p1[i].w, sp))));
                sn  = fmaf(q1[i].x,q1[i].x, fmaf(q1[i].y,q1[i].y, fmaf(q1[i].z,q1[i].z, fmaf(q1[i].w,q1[i].w, sn))));
                dap = fmaf(a1[i].x,p1[i].x, fmaf(a1[i].y,p1[i].y, fmaf(a1[i].z,p1[i].z, fmaf(a1[i].w,p1[i].w, dap))));
                dan = fmaf(a1[i].x,q1[i].x, fmaf(a1[i].y,q1[i].y, fmaf(a1[i].z,q1[i].z, fmaf(a1[i].w,q1[i].w, dan))));
            }
#pragma unroll
            for (int o = 1; o < 16; o <<= 1) {
                sa  += __shfl_xor(sa,  o);
                sp  += __shfl_xor(sp,  o);
                sn  += __shfl_xor(sn,  o);
                dap += __shfl_xor(dap, o);
                dan += __shfl_xor(dan, o);
            }
            if (seg == 0) {
                float na = fmaxf(sqrtf(sa), EPSN);
                float np = fmaxf(sqrtf(sp), EPSN);
                float nn = fmaxf(sqrtf(sn), EPSN);
                float posd = 1.f - dap / (na * np);
                float negd = 1.f - dan / (na * nn);
                tri += fmaxf(posd - negd + MARGIN, 0.f);
            }
        }
    }
    tri += __shfl_xor(tri, 16);   // combine lanes 0,16,32,48 (seg==0 holders)
    tri += __shfl_xor(tri, 32);
    if (lane == 0) red[wid] = tri;
    __syncthreads();
    if (t == 0) atomicAdd(&scal[0], red[0] + red[1] + red[2] + red[3]);
}

// ---------------- Kernel 2: per-class sums + counts ----------------
// 8 rows per iteration for MLP; each thread owns float2 column slot exclusively.
__global__ __launch_bounds__(256) void k_segsum(const float* __restrict__ E,
                                                const int* __restrict__ L,
                                                float* __restrict__ sums,
                                                int* __restrict__ counts, int N) {
    __shared__ float acc[NCLS * DIM];
    __shared__ int cl[NCLS];
    int t = threadIdx.x;
    for (int i = t; i < NCLS * DIM; i += 256) acc[i] = 0.f;
    if (t < NCLS) cl[t] = 0;
    __syncthreads();
    for (int r = blockIdx.x * 8; r < N; r += gridDim.x * 8) {
        int l[8];
        float2 v[8];
#pragma unroll
        for (int i = 0; i < 8; ++i) l[i] = L[r + i];
#pragma unroll
        for (int i = 0; i < 8; ++i)
            v[i] = *((const float2*)(E + (size_t)(r + i) * DIM) + t);
#pragma unroll
        for (int i = 0; i < 8; ++i) {
            float2* p = (float2*)&acc[l[i] * DIM] + t;
            p->x += v[i].x; p->y += v[i].y;
        }
        if (t == 0) {
#pragma unroll
            for (int i = 0; i < 8; ++i) cl[l[i]]++;
        }
    }
    __syncthreads();
    for (int i = t; i < NCLS * DIM; i += 256) atomicAdd(&sums[i], acc[i]);
    if (t < NCLS) atomicAdd(&counts[t], cl[t]);
}

// ---------------- Kernel 3 (tiny): centroids, normalize, pair matrix, cnt, n_terms ----------------
__global__ __launch_bounds__(256) void k_centroid(const float* __restrict__ sums,
                                                  const int* __restrict__ counts,
                                                  float* __restrict__ ncn_g,
                                                  float* __restrict__ pairf_g,
                                                  float* __restrict__ cntf_g,
                                                  float* __restrict__ scal) {
    __shared__ float ncn[NCLS * DIM];
    __shared__ float red[256];
    int t = threadIdx.x;
    for (int c = 0; c < NCLS; ++c) {
        float inv = 1.f / fmaxf((float)counts[c], 1.f);
        float s0 = sums[c * DIM + t] * inv;
        float s1 = sums[c * DIM + 256 + t] * inv;
        ncn[c * DIM + t] = s0;
        ncn[c * DIM + 256 + t] = s1;
        red[t] = s0 * s0 + s1 * s1;
        __syncthreads();
        for (int o = 128; o > 0; o >>= 1) { if (t < o) red[t] += red[t + o]; __syncthreads(); }
        float rs = 1.f / fmaxf(sqrtf(red[0]), EPSN);
        ncn[c * DIM + t] *= rs;
        ncn[c * DIM + 256 + t] *= rs;
        __syncthreads();
    }
    for (int i = t; i < NCLS * DIM; i += 256) ncn_g[i] = ncn[i];
    __syncthreads();
    // pair matrix in full fp32 (binary decisions are sensitive -> no bf16 here)
    int i = t >> 4, j = t & 15;
    float dot = 0.f;
    for (int d = 0; d < DIM; ++d) dot += ncn[i * DIM + d] * ncn[j * DIM + d];
    float cd = 1.f - dot;
    float pf = (cd <= BETA && i != j && counts[i] > 0 && counts[j] > 0) ? 1.f : 0.f;
    pairf_g[t] = pf;
    red[t] = pf;
    __syncthreads();
    if (t < NCLS) {
        float s = 0.f;
        for (int k = 0; k < NCLS; ++k) s += red[t * 16 + k];
        cntf_g[t] = s;
    }
    __syncthreads();
    if (t == 0) {
        float nt = 0.f;
        for (int k = 0; k < NCLS; ++k) nt += cntf_g[k] * (float)counts[k];
        scal[3] = nt;
        scal[4] = 1.f / fmaxf(nt, 1.f);
    }
}

// ---------------- Kernel 4: D = ê·ncn^T via bf16 MFMA; intra/inter partials ----------------
__global__ __launch_bounds__(256) void k_atn(const float* __restrict__ E,
                                             const int* __restrict__ L,
                                             const float* __restrict__ ncn,
                                             const float* __restrict__ pairf,
                                             const float* __restrict__ cntf,
                                             float* __restrict__ scal, int N) {
    __shared__ float pr[NCLS * NCLS];
    __shared__ float cf[NCLS];
    __shared__ float red[8];
    int t = threadIdx.x, lane = t & 63, wid = t >> 6;
    pr[t] = pairf[t];
    if (t < NCLS) cf[t] = cntf[t];
    __syncthreads();

    int col = lane & 15;      // A-row within tile == B-col (class)
    int kg = lane >> 4;       // k-group 0..3
    short8 bfr[16];           // B fragments for all 16 K-steps, held in VGPRs
#pragma unroll
    for (int s = 0; s < 16; ++s) {
        const float4* q = (const float4*)(ncn + col * DIM + s * 32 + kg * 8);
        bfr[s] = pack8(q[0], q[1]);
    }

    float inter = 0.f, intra = 0.f;
    int gw = blockIdx.x * 4 + wid, nw = gridDim.x * 4;
    int ntile = N >> 4;
    for (int tile = gw; tile < ntile; tile += nw) {
        int rowb = tile << 4;
        const float* ar = E + (size_t)(rowb + col) * DIM + kg * 8;
        f32x4 acc0 = {0.f, 0.f, 0.f, 0.f}, acc1 = {0.f, 0.f, 0.f, 0.f};
        float ss0 = 0.f, ss1 = 0.f;
#pragma unroll
        for (int s = 0; s < 16; s += 2) {
            float4 x0 = *(const float4*)(ar + s * 32);
            float4 x1 = *(const float4*)(ar + s * 32 + 4);
            float4 y0 = *(const float4*)(ar + (s + 1) * 32);
            float4 y1 = *(const float4*)(ar + (s + 1) * 32 + 4);
            ss0 = fmaf(x0.x, x0.x, ss0); ss0 = fmaf(x0.y, x0.y, ss0);
            ss0 = fmaf(x0.z, x0.z, ss0); ss0 = fmaf(x0.w, x0.w, ss0);
            ss0 = fmaf(x1.x, x1.x, ss0); ss0 = fmaf(x1.y, x1.y, ss0);
            ss0 = fmaf(x1.z, x1.z, ss0); ss0 = fmaf(x1.w, x1.w, ss0);
            ss1 = fmaf(y0.x, y0.x, ss1); ss1 = fmaf(y0.y, y0.y, ss1);
            ss1 = fmaf(y0.z, y0.z, ss1); ss1 = fmaf(y0.w, y0.w, ss1);
            ss1 = fmaf(y1.x, y1.x, ss1); ss1 = fmaf(y1.y, y1.y, ss1);
            ss1 = fmaf(y1.w, y1.w, ss1); ss1 = fmaf(y1.z, y1.z, ss1);
            acc0 = __builtin_amdgcn_mfma_f32_16x16x32_bf16(pack8(x0, x1), bfr[s],     acc0, 0, 0, 0);
            acc1 = __builtin_amdgcn_mfma_f32_16x16x32_bf16(pack8(y0, y1), bfr[s + 1], acc1, 0, 0, 0);
        }
        f32x4 acc = acc0 + acc1;
        float ss = ss0 + ss1;
        // lane holds sumsq partial of row (lane&15) over its k-quarter; combine quarters
        ss += __shfl_xor(ss, 16);
        ss += __shfl_xor(ss, 32);
#pragma unroll
        for (int reg = 0; reg < 4; ++reg) {
            int row = kg * 4 + reg;            // C/D: col=lane&15, row=(lane>>4)*4+reg
            float s2 = __shfl(ss, row);        // lane 'row' holds sumsq of row 'row'
            float rinv = 1.f / fmaxf(sqrtf(s2), EPSN);
            float d = 1.f - acc[reg] * rinv;
            int lab = L[rowb + row];
            inter += pr[lab * 16 + col] * fmaxf(BETA - d, 0.f);
            if (col == lab) intra += cf[lab] * fmaxf(d - ALPHA, 0.f);
        }
    }
#pragma unroll
    for (int o = 32; o > 0; o >>= 1) {
        inter += __shfl_xor(inter, o);
        intra += __shfl_xor(intra, o);
    }
    if (lane == 0) { red[wid] = intra; red[4 + wid] = inter; }
    __syncthreads();
    if (t == 0) {
        atomicAdd(&scal[1], red[0] + red[1] + red[2] + red[3]);
        atomicAdd(&scal[2], red[4] + red[5] + red[6] + red[7]);
    }
}

// ---------------- Kernel 5: combine ----------------
__global__ void k_final(const float* __restrict__ scal, float* __restrict__ out, float invN) {
    float tri = scal[0] * invN;
    float atn = (scal[3] > 0.f) ? (scal[1] + scal[2]) * scal[4] : 0.f;
    out[0] = tri + atn;
}

extern "C" void kernel_launch(void* const* d_in, const int* in_sizes, int n_in,
                              void* d_out, int out_size, void* d_ws, size_t ws_size,
                              hipStream_t stream) {
    const float* A = (const float*)d_in[0];
    const float* P = (const float*)d_in[1];
    const float* Q = (const float*)d_in[2];
    const float* E = (const float*)d_in[3];
    const int*   L = (const int*)d_in[4];
    int N = in_sizes[0] / DIM;

    char* ws = (char*)d_ws;
    float* sums   = (float*)ws;             // 8192 f32 = 32768 B
    int*   counts = (int*)(ws + 32768);     // 16 i32
    float* scal   = (float*)(ws + 32832);   // [0]=tri [1]=intra [2]=inter [3]=n_terms [4]=1/max(n,1)
    float* ncn    = (float*)(ws + 36864);   // 8192 f32 normalized centroids
    float* pairf  = (float*)(ws + 69632);   // 256 f32
    float* cntf   = (float*)(ws + 70656);   // 16 f32

    (void)hipMemsetAsync(d_ws, 0, 36864, stream); // zero accumulators every call

    k_triplet <<<2048, 256, 0, stream>>>(A, P, Q, scal, N);
    k_segsum  <<<512,  256, 0, stream>>>(E, L, sums, counts, N);
    k_centroid<<<1,    256, 0, stream>>>(sums, counts, ncn, pairf, cntf, scal);
    k_atn     <<<512,  256, 0, stream>>>(E, L, ncn, pairf, cntf, scal, N);
    k_final   <<<1, 1, 0, stream>>>(scal, (float*)d_out, 1.f / (float)N);
}

// Round 6
// 172.922 us; speedup vs baseline: 1.6602x; 1.0795x over previous
//
#include <hip/hip_runtime.h>

#define EPSN   1e-8f
#define MARGIN 0.2f
#define ALPHA  0.1f
#define BETA   1.05f
#define DIM    512
#define NCLS   16

typedef __attribute__((ext_vector_type(8))) short short8;
typedef __attribute__((ext_vector_type(4))) float f32x4;
typedef __attribute__((ext_vector_type(4))) float nf4;   // native vec for nontemporal builtins

__device__ __forceinline__ unsigned short f2bf(float f) {
    unsigned u = __float_as_uint(f);
    return (unsigned short)((u + 0x7FFFu + ((u >> 16) & 1u)) >> 16);  // RNE
}
__device__ __forceinline__ short8 pack8(float4 x0, float4 x1) {
    short8 r;
    r[0] = (short)f2bf(x0.x); r[1] = (short)f2bf(x0.y);
    r[2] = (short)f2bf(x0.z); r[3] = (short)f2bf(x0.w);
    r[4] = (short)f2bf(x1.x); r[5] = (short)f2bf(x1.y);
    r[6] = (short)f2bf(x1.z); r[7] = (short)f2bf(x1.w);
    return r;
}
__device__ __forceinline__ short8 pack8v(nf4 x0, nf4 x1) {
    short8 r;
    r[0] = (short)f2bf(x0.x); r[1] = (short)f2bf(x0.y);
    r[2] = (short)f2bf(x0.z); r[3] = (short)f2bf(x0.w);
    r[4] = (short)f2bf(x1.x); r[5] = (short)f2bf(x1.y);
    r[6] = (short)f2bf(x1.z); r[7] = (short)f2bf(x1.w);
    return r;
}

// ---------------- Kernel 1: FUSED triplet + segsum ----------------
// Interleaved block-type split: (blockIdx&3)==3 -> segsum (512 blocks),
// else triplet (1536 blocks). Both memory streams run concurrently.
// Triplet path: R5 structure (nt loads, 2-deep pipeline, 16-lane-group reduce).
// Segsum path: per-thread-exclusive float2 column slot into 32KB LDS acc.
__global__ __launch_bounds__(256) void k_fused(const float* __restrict__ A,
                                               const float* __restrict__ P,
                                               const float* __restrict__ Q,
                                               const float* __restrict__ E,
                                               const int* __restrict__ L,
                                               float* __restrict__ sums,
                                               int* __restrict__ counts,
                                               float* __restrict__ scal, int N) {
    __shared__ float acc[NCLS * DIM];   // segsum accumulator; triplet uses acc[0..3] as red
    __shared__ int cl[NCLS];
    int t = threadIdx.x, lane = t & 63, wid = t >> 6;
    int bid = blockIdx.x;
    bool is_seg = (bid & 3) == 3;

    if (!is_seg) {
        // ---------------- triplet path ----------------
        int trank = bid - (bid >> 2);          // rank among 1536 triplet blocks
        const int NT = 1536;
        int g = lane >> 4, seg = lane & 15;
        int gw = trank * 4 + wid, nw = NT * 4; // 6144 waves
        int nquad = N >> 2;
        float tri = 0.f;
        for (int quad = gw; quad < nquad; quad += 2 * nw) {
            int quadB = quad + nw;
            bool hasB = quadB < nquad;
            size_t base0 = (size_t)(quad * 4 + g) * DIM + seg * 4;
            size_t base1 = hasB ? ((size_t)(quadB * 4 + g) * DIM + seg * 4) : base0;
            nf4 a0[8], p0[8], q0[8], a1[8], p1[8], q1[8];
#pragma unroll
            for (int i = 0; i < 8; ++i) a0[i] = __builtin_nontemporal_load((const nf4*)(A + base0 + i * 64));
#pragma unroll
            for (int i = 0; i < 8; ++i) p0[i] = __builtin_nontemporal_load((const nf4*)(P + base0 + i * 64));
#pragma unroll
            for (int i = 0; i < 8; ++i) q0[i] = __builtin_nontemporal_load((const nf4*)(Q + base0 + i * 64));
#pragma unroll
            for (int i = 0; i < 8; ++i) a1[i] = __builtin_nontemporal_load((const nf4*)(A + base1 + i * 64));
#pragma unroll
            for (int i = 0; i < 8; ++i) p1[i] = __builtin_nontemporal_load((const nf4*)(P + base1 + i * 64));
#pragma unroll
            for (int i = 0; i < 8; ++i) q1[i] = __builtin_nontemporal_load((const nf4*)(Q + base1 + i * 64));
            {
                float sa = 0, sp = 0, sn = 0, dap = 0, dan = 0;
#pragma unroll
                for (int i = 0; i < 8; ++i) {
                    sa  = fmaf(a0[i].x,a0[i].x, fmaf(a0[i].y,a0[i].y, fmaf(a0[i].z,a0[i].z, fmaf(a0[i].w,a0[i].w, sa))));
                    sp  = fmaf(p0[i].x,p0[i].x, fmaf(p0[i].y,p0[i].y, fmaf(p0[i].z,p0[i].z, fmaf(p0[i].w,p0[i].w, sp))));
                    sn  = fmaf(q0[i].x,q0[i].x, fmaf(q0[i].y,q0[i].y, fmaf(q0[i].z,q0[i].z, fmaf(q0[i].w,q0[i].w, sn))));
                    dap = fmaf(a0[i].x,p0[i].x, fmaf(a0[i].y,p0[i].y, fmaf(a0[i].z,p0[i].z, fmaf(a0[i].w,p0[i].w, dap))));
                    dan = fmaf(a0[i].x,q0[i].x, fmaf(a0[i].y,q0[i].y, fmaf(a0[i].z,q0[i].z, fmaf(a0[i].w,q0[i].w, dan))));
                }
#pragma unroll
                for (int o = 1; o < 16; o <<= 1) {
                    sa  += __shfl_xor(sa,  o);
                    sp  += __shfl_xor(sp,  o);
                    sn  += __shfl_xor(sn,  o);
                    dap += __shfl_xor(dap, o);
                    dan += __shfl_xor(dan, o);
                }
                if (seg == 0) {
                    float na = fmaxf(sqrtf(sa), EPSN);
                    float np = fmaxf(sqrtf(sp), EPSN);
                    float nn = fmaxf(sqrtf(sn), EPSN);
                    tri += fmaxf((1.f - dap / (na * np)) - (1.f - dan / (na * nn)) + MARGIN, 0.f);
                }
            }
            if (hasB) {
                float sa = 0, sp = 0, sn = 0, dap = 0, dan = 0;
#pragma unroll
                for (int i = 0; i < 8; ++i) {
                    sa  = fmaf(a1[i].x,a1[i].x, fmaf(a1[i].y,a1[i].y, fmaf(a1[i].z,a1[i].z, fmaf(a1[i].w,a1[i].w, sa))));
                    sp  = fmaf(p1[i].x,p1[i].x, fmaf(p1[i].y,p1[i].y, fmaf(p1[i].z,p1[i].z, fmaf(p1[i].w,p1[i].w, sp))));
                    sn  = fmaf(q1[i].x,q1[i].x, fmaf(q1[i].y,q1[i].y, fmaf(q1[i].z,q1[i].z, fmaf(q1[i].w,q1[i].w, sn))));
                    dap = fmaf(a1[i].x,p1[i].x, fmaf(a1[i].y,p1[i].y, fmaf(a1[i].z,p1[i].z, fmaf(a1[i].w,p1[i].w, dap))));
                    dan = fmaf(a1[i].x,q1[i].x, fmaf(a1[i].y,q1[i].y, fmaf(a1[i].z,q1[i].z, fmaf(a1[i].w,q1[i].w, dan))));
                }
#pragma unroll
                for (int o = 1; o < 16; o <<= 1) {
                    sa  += __shfl_xor(sa,  o);
                    sp  += __shfl_xor(sp,  o);
                    sn  += __shfl_xor(sn,  o);
                    dap += __shfl_xor(dap, o);
                    dan += __shfl_xor(dan, o);
                }
                if (seg == 0) {
                    float na = fmaxf(sqrtf(sa), EPSN);
                    float np = fmaxf(sqrtf(sp), EPSN);
                    float nn = fmaxf(sqrtf(sn), EPSN);
                    tri += fmaxf((1.f - dap / (na * np)) - (1.f - dan / (na * nn)) + MARGIN, 0.f);
                }
            }
        }
        tri += __shfl_xor(tri, 16);
        tri += __shfl_xor(tri, 32);
        if (lane == 0) acc[wid] = tri;
        __syncthreads();
        if (t == 0) atomicAdd(&scal[0], acc[0] + acc[1] + acc[2] + acc[3]);
    } else {
        // ---------------- segsum path ----------------
        int sb = bid >> 2;                     // rank among 512 segsum blocks
        const int NS = 512;
        for (int i = t; i < NCLS * DIM; i += 256) acc[i] = 0.f;
        if (t < NCLS) cl[t] = 0;
        __syncthreads();
        for (int r = sb * 8; r < N; r += NS * 8) {
            int l[8];
            float2 v[8];
#pragma unroll
            for (int i = 0; i < 8; ++i) l[i] = L[r + i];
#pragma unroll
            for (int i = 0; i < 8; ++i)
                v[i] = *((const float2*)(E + (size_t)(r + i) * DIM) + t);
#pragma unroll
            for (int i = 0; i < 8; ++i) {
                float2* p = (float2*)&acc[l[i] * DIM] + t;
                p->x += v[i].x; p->y += v[i].y;
            }
            if (t == 0) {
#pragma unroll
                for (int i = 0; i < 8; ++i) cl[l[i]]++;
            }
        }
        __syncthreads();
        for (int i = t; i < NCLS * DIM; i += 256) atomicAdd(&sums[i], acc[i]);
        if (t < NCLS) atomicAdd(&counts[t], cl[t]);
    }
}

// ---------------- Kernel 2: ATN with per-block centroid prologue ----------------
// Every block redundantly computes ncn/pair/cnt from sums+counts (33KB from L2,
// wave-parallel). Block 0 additionally publishes n_terms to scal[3]/[4].
__global__ __launch_bounds__(256) void k_atn(const float* __restrict__ E,
                                             const int* __restrict__ L,
                                             const float* __restrict__ sums,
                                             const int* __restrict__ counts,
                                             float* __restrict__ scal, int N) {
    __shared__ float ncn[NCLS * DIM];   // 32 KB normalized centroids
    __shared__ float pr[NCLS * NCLS];
    __shared__ float cf[NCLS];
    __shared__ float red[8];
    int t = threadIdx.x, lane = t & 63, wid = t >> 6;

    // --- prologue: centroids (16 groups of 16 threads; group c = class c) ---
    {
        int c = t >> 4, s = t & 15;
        float inv = 1.f / fmaxf((float)counts[c], 1.f);
        float4 v[8];
        float ssq = 0.f;
#pragma unroll
        for (int i = 0; i < 8; ++i) {
            v[i] = *(const float4*)(sums + c * DIM + s * 32 + i * 4);
            v[i].x *= inv; v[i].y *= inv; v[i].z *= inv; v[i].w *= inv;
            ssq = fmaf(v[i].x, v[i].x, fmaf(v[i].y, v[i].y, fmaf(v[i].z, v[i].z, fmaf(v[i].w, v[i].w, ssq))));
        }
#pragma unroll
        for (int o = 1; o < 16; o <<= 1) ssq += __shfl_xor(ssq, o);
        float rs = 1.f / fmaxf(sqrtf(ssq), EPSN);
#pragma unroll
        for (int i = 0; i < 8; ++i) {
            float4* d = (float4*)&ncn[c * DIM + s * 32 + i * 4];
            d->x = v[i].x * rs; d->y = v[i].y * rs; d->z = v[i].z * rs; d->w = v[i].w * rs;
        }
    }
    __syncthreads();
    // --- pair matrix (fp32; binary threshold decisions) ---
    {
        int i = t >> 4, j = t & 15;
        float dot = 0.f;
        for (int d = 0; d < DIM; d += 4) {
            float4 a = *(const float4*)&ncn[i * DIM + d];
            float4 b = *(const float4*)&ncn[j * DIM + d];
            dot = fmaf(a.x, b.x, fmaf(a.y, b.y, fmaf(a.z, b.z, fmaf(a.w, b.w, dot))));
        }
        float cd = 1.f - dot;
        float pf = (cd <= BETA && i != j && counts[i] > 0 && counts[j] > 0) ? 1.f : 0.f;
        pr[t] = pf;
    }
    __syncthreads();
    if (t < NCLS) {
        float s = 0.f;
#pragma unroll
        for (int k = 0; k < NCLS; ++k) s += pr[t * 16 + k];
        cf[t] = s;
    }
    __syncthreads();
    if (blockIdx.x == 0 && t == 0) {
        float nt = 0.f;
#pragma unroll
        for (int k = 0; k < NCLS; ++k) nt += cf[k] * (float)counts[k];
        scal[3] = nt;
        scal[4] = 1.f / fmaxf(nt, 1.f);
    }

    // --- main loop: D = ê·ncn^T via bf16 MFMA ---
    int col = lane & 15;      // A-row within tile == B-col (class)
    int kg = lane >> 4;       // k-group 0..3
    short8 bfr[16];
#pragma unroll
    for (int s = 0; s < 16; ++s) {
        const float4* q = (const float4*)&ncn[col * DIM + s * 32 + kg * 8];
        bfr[s] = pack8(q[0], q[1]);
    }

    float inter = 0.f, intra = 0.f;
    int gw = blockIdx.x * 4 + wid, nw = gridDim.x * 4;
    int ntile = N >> 4;
    for (int tile = gw; tile < ntile; tile += nw) {
        int rowb = tile << 4;
        const float* ar = E + (size_t)(rowb + col) * DIM + kg * 8;
        f32x4 acc0 = {0.f, 0.f, 0.f, 0.f}, acc1 = {0.f, 0.f, 0.f, 0.f};
        float ss0 = 0.f, ss1 = 0.f;
#pragma unroll
        for (int s = 0; s < 16; s += 2) {
            float4 x0 = *(const float4*)(ar + s * 32);
            float4 x1 = *(const float4*)(ar + s * 32 + 4);
            float4 y0 = *(const float4*)(ar + (s + 1) * 32);
            float4 y1 = *(const float4*)(ar + (s + 1) * 32 + 4);
            ss0 = fmaf(x0.x, x0.x, ss0); ss0 = fmaf(x0.y, x0.y, ss0);
            ss0 = fmaf(x0.z, x0.z, ss0); ss0 = fmaf(x0.w, x0.w, ss0);
            ss0 = fmaf(x1.x, x1.x, ss0); ss0 = fmaf(x1.y, x1.y, ss0);
            ss0 = fmaf(x1.z, x1.z, ss0); ss0 = fmaf(x1.w, x1.w, ss0);
            ss1 = fmaf(y0.x, y0.x, ss1); ss1 = fmaf(y0.y, y0.y, ss1);
            ss1 = fmaf(y0.z, y0.z, ss1); ss1 = fmaf(y0.w, y0.w, ss1);
            ss1 = fmaf(y1.x, y1.x, ss1); ss1 = fmaf(y1.y, y1.y, ss1);
            ss1 = fmaf(y1.w, y1.w, ss1); ss1 = fmaf(y1.z, y1.z, ss1);
            acc0 = __builtin_amdgcn_mfma_f32_16x16x32_bf16(pack8(x0, x1), bfr[s],     acc0, 0, 0, 0);
            acc1 = __builtin_amdgcn_mfma_f32_16x16x32_bf16(pack8(y0, y1), bfr[s + 1], acc1, 0, 0, 0);
        }
        f32x4 acc = acc0 + acc1;
        float ss = ss0 + ss1;
        ss += __shfl_xor(ss, 16);
        ss += __shfl_xor(ss, 32);
#pragma unroll
        for (int reg = 0; reg < 4; ++reg) {
            int row = kg * 4 + reg;            // C/D: col=lane&15, row=(lane>>4)*4+reg
            float s2 = __shfl(ss, row);
            float rinv = 1.f / fmaxf(sqrtf(s2), EPSN);
            float d = 1.f - acc[reg] * rinv;
            int lab = L[rowb + row];
            inter += pr[lab * 16 + col] * fmaxf(BETA - d, 0.f);
            if (col == lab) intra += cf[lab] * fmaxf(d - ALPHA, 0.f);
        }
    }
#pragma unroll
    for (int o = 32; o > 0; o >>= 1) {
        inter += __shfl_xor(inter, o);
        intra += __shfl_xor(intra, o);
    }
    if (lane == 0) { red[wid] = intra; red[4 + wid] = inter; }
    __syncthreads();
    if (t == 0) {
        atomicAdd(&scal[1], red[0] + red[1] + red[2] + red[3]);
        atomicAdd(&scal[2], red[4] + red[5] + red[6] + red[7]);
    }
}

// ---------------- Kernel 3: combine ----------------
__global__ void k_final(const float* __restrict__ scal, float* __restrict__ out, float invN) {
    float tri = scal[0] * invN;
    float atn = (scal[3] > 0.f) ? (scal[1] + scal[2]) * scal[4] : 0.f;
    out[0] = tri + atn;
}

extern "C" void kernel_launch(void* const* d_in, const int* in_sizes, int n_in,
                              void* d_out, int out_size, void* d_ws, size_t ws_size,
                              hipStream_t stream) {
    const float* A = (const float*)d_in[0];
    const float* P = (const float*)d_in[1];
    const float* Q = (const float*)d_in[2];
    const float* E = (const float*)d_in[3];
    const int*   L = (const int*)d_in[4];
    int N = in_sizes[0] / DIM;

    char* ws = (char*)d_ws;
    float* sums   = (float*)ws;             // 8192 f32 = 32768 B
    int*   counts = (int*)(ws + 32768);     // 16 i32
    float* scal   = (float*)(ws + 32832);   // [0]=tri [1]=intra [2]=inter [3]=n_terms [4]=1/max(n,1)

    (void)hipMemsetAsync(d_ws, 0, 36864, stream); // zero accumulators every call

    k_fused <<<2048, 256, 0, stream>>>(A, P, Q, E, L, sums, counts, scal, N);
    k_atn   <<<512,  256, 0, stream>>>(E, L, sums, counts, scal, N);
    k_final <<<1, 1, 0, stream>>>(scal, (float*)d_out, 1.f / (float)N);
}